// Round 1
// 264.715 us; speedup vs baseline: 1.2863x; 1.2863x over previous
//
#include <hip/hip_runtime.h>

#define Bc 8
#define Tc 4096
#define Dc 768
#define Hc 12
#define HDc 64
#define Kc 32
#define TD3 2304
#define WQKV_F (TD3 * Dc)          // 1,769,472 floats
#define WALL_F ((TD3 + Dc) * Dc)   // 2,359,296 floats (wqkv + wout)

typedef __attribute__((ext_vector_type(8))) short short8;
typedef __attribute__((ext_vector_type(4))) short short4v;
typedef __attribute__((ext_vector_type(4))) float float4v;

__device__ __forceinline__ float bf2f(unsigned short u) {
    unsigned v = ((unsigned)u) << 16;
    return __builtin_bit_cast(float, v);
}
__device__ __forceinline__ unsigned short f2bf(float f) {
    unsigned u = __builtin_bit_cast(unsigned, f);
    u += 0x7FFFu + ((u >> 16) & 1u);   // RNE
    return (unsigned short)(u >> 16);
}

// split 8 fp32 into bf16 hi + bf16 lo fragments (hi+lo ~ fp32 precision)
__device__ __forceinline__ void split8(const float* p, short8& hi, short8& lo) {
#pragma unroll
    for (int i = 0; i < 8; ++i) {
        unsigned short h = f2bf(p[i]);
        hi[i] = (short)h;
        lo[i] = (short)f2bf(p[i] - bf2f(h));
    }
}

// ---------------------------------------------------------------------------
// K1: pb[tc][b][kk][d] = sum_{t in 256-chunk tc} sb[b,t,kk] * x[b,t,d]
// (unchanged, validated)
// ---------------------------------------------------------------------------
__global__ __launch_bounds__(256) void k1_xspec(const float* __restrict__ x,
                                                const float* __restrict__ sb,
                                                float* __restrict__ pb) {
    __shared__ float xt[32 * 193];   // x tile,  stride 193 -> <=2-way conflicts
    __shared__ float st[32 * 33];    // sb tile, stride 33  -> <=2-way conflicts

    int tid  = threadIdx.x;
    int w    = tid >> 6;
    int lane = tid & 63;
    int col  = lane & 15;
    int quad = lane >> 4;

    int bid = blockIdx.x;            // 512 = 8b x 4dt x 16tc
    int b  = bid >> 6;
    int dt = (bid >> 4) & 3;
    int tc = bid & 15;
    int d0 = dt * 192;
    size_t bT = (size_t)b * Tc + (size_t)tc * 256;

    float4v acc[2][3];
#pragma unroll
    for (int mi = 0; mi < 2; ++mi)
#pragma unroll
        for (int ni = 0; ni < 3; ++ni) acc[mi][ni] = (float4v){0.f, 0.f, 0.f, 0.f};

    for (int ks = 0; ks < 8; ++ks) {
        __syncthreads();   // previous sub-tile's reads complete
        // stage x[32t x 192d]: 1536 float4, 6 per thread, coalesced
#pragma unroll
        for (int i = 0; i < 6; ++i) {
            int f4  = tid + i * 256;
            int row = f4 / 48, c4 = f4 % 48;
            float4v v = *(const float4v*)&x[(bT + ks * 32 + row) * Dc + d0 + c4 * 4];
#pragma unroll
            for (int q = 0; q < 4; ++q) xt[row * 193 + c4 * 4 + q] = v[q];
        }
        // stage sb[32t x 32k]: 256 float4, 1 per thread, coalesced
        {
            int row = tid >> 3, c4 = tid & 7;
            float4v v = *(const float4v*)&sb[(bT + ks * 32 + row) * Kc + c4 * 4];
#pragma unroll
            for (int q = 0; q < 4; ++q) st[row * 33 + c4 * 4 + q] = v[q];
        }
        __syncthreads();

        // A fragments (sb)
        short8 ah[2], al[2];
#pragma unroll
        for (int mi = 0; mi < 2; ++mi) {
            float av[8];
#pragma unroll
            for (int j = 0; j < 8; ++j)
                av[j] = st[(quad * 8 + j) * 33 + mi * 16 + col];
            split8(av, ah[mi], al[mi]);
        }
        // B fragments (x) + MFMA
#pragma unroll
        for (int ni = 0; ni < 3; ++ni) {
            int nc = (w * 3 + ni) * 16 + col;
            float bv[8];
#pragma unroll
            for (int j = 0; j < 8; ++j)
                bv[j] = xt[(quad * 8 + j) * 193 + nc];
            short8 bh, bl;
            split8(bv, bh, bl);
#pragma unroll
            for (int mi = 0; mi < 2; ++mi) {
                acc[mi][ni] = __builtin_amdgcn_mfma_f32_16x16x32_bf16(ah[mi], bh, acc[mi][ni], 0, 0, 0);
                acc[mi][ni] = __builtin_amdgcn_mfma_f32_16x16x32_bf16(al[mi], bh, acc[mi][ni], 0, 0, 0);
                acc[mi][ni] = __builtin_amdgcn_mfma_f32_16x16x32_bf16(ah[mi], bl, acc[mi][ni], 0, 0, 0);
            }
        }
    }

    // exclusive write to pb[tc]
    float* pbp = pb + (size_t)tc * (Bc * Kc * Dc);
#pragma unroll
    for (int mi = 0; mi < 2; ++mi)
#pragma unroll
        for (int ni = 0; ni < 3; ++ni)
#pragma unroll
            for (int r = 0; r < 4; ++r) {
                int kk = mi * 16 + quad * 4 + r;
                int dd = d0 + (w * 3 + ni) * 16 + col;
                pbp[((size_t)(b * Kc + kk)) * Dc + dd] = acc[mi][ni][r];
            }
}

// reduce 16 partials -> xs bf16 hi/lo planes (xs has no other consumer)
__global__ __launch_bounds__(256) void k1r_reduce(const float* __restrict__ pb,
                                                  short* __restrict__ xs_hi,
                                                  short* __restrict__ xs_lo) {
    int i = (blockIdx.x * 256 + threadIdx.x) * 4;   // 192 blocks -> 196608 floats
    float4v s = (float4v){0.f, 0.f, 0.f, 0.f};
#pragma unroll
    for (int p = 0; p < 16; ++p) {
        float4v v = *(const float4v*)(pb + (size_t)p * (Bc * Kc * Dc) + i);
#pragma unroll
        for (int q = 0; q < 4; ++q) s[q] += v[q];
    }
    short4v h, l;
#pragma unroll
    for (int q = 0; q < 4; ++q) {
        unsigned short hb = f2bf(s[q]);
        h[q] = (short)hb;
        l[q] = (short)f2bf(s[q] - bf2f(hb));
    }
    *(short4v*)(xs_hi + i) = h;
    *(short4v*)(xs_lo + i) = l;
}

// convert wqkv (2304x768) + wout (768x768) fp32 -> bf16 hi/lo planes.
// Runs after k1r; output aliases the then-dead pb region.
__global__ __launch_bounds__(256) void kconv(const float* __restrict__ wqkv,
                                             const float* __restrict__ wout,
                                             short* __restrict__ w_hi,
                                             short* __restrict__ w_lo) {
    int i = (blockIdx.x * 256 + threadIdx.x) * 4;   // 2304 blocks -> 2,359,296 floats
    const float* src = (i < WQKV_F) ? (wqkv + i) : (wout + (i - WQKV_F));
    float4v v = *(const float4v*)src;
    short4v h, l;
#pragma unroll
    for (int q = 0; q < 4; ++q) {
        unsigned short hb = f2bf(v[q]);
        h[q] = (short)hb;
        l[q] = (short)f2bf(v[q] - bf2f(hb));
    }
    *(short4v*)(w_hi + i) = h;
    *(short4v*)(w_lo + i) = l;
}

// ---------------------------------------------------------------------------
// K2: c1[r, j] = sum_c xs[r, c] * wqkv[j, c] — pure-MFMA bf16-plane GEMM.
// Wave tile 32(M)x16(N); grid 288 = 8 mb x 36 nb, 4 waves split N within block.
// Per K-32 step: 6x 16B plane loads + 6 MFMA, zero conversion VALU.
// ---------------------------------------------------------------------------
__global__ __launch_bounds__(256) void k2_qkv(const short* __restrict__ xs_hi,
                                              const short* __restrict__ xs_lo,
                                              const short* __restrict__ w_hi,
                                              const short* __restrict__ w_lo,
                                              float* __restrict__ c1) {
    int lane = threadIdx.x & 63;
    int w    = threadIdx.x >> 6;
    int m    = lane & 15, quad = lane >> 4;
    int mb = blockIdx.x & 7;           // same-XCD neighbors (bid, bid+8) share mb -> A reuse
    int nb = blockIdx.x >> 3;
    int m0 = mb * 32;
    int n0 = nb * 64 + w * 16;

    const short* a0h = xs_hi + (size_t)(m0 + m) * Dc + quad * 8;
    const short* a0l = xs_lo + (size_t)(m0 + m) * Dc + quad * 8;
    const short* a1h = a0h + (size_t)16 * Dc;
    const short* a1l = a0l + (size_t)16 * Dc;
    const short* bhp = w_hi + (size_t)(n0 + m) * Dc + quad * 8;
    const short* blp = w_lo + (size_t)(n0 + m) * Dc + quad * 8;

    float4v acc0 = (float4v){0.f, 0.f, 0.f, 0.f};
    float4v acc1 = (float4v){0.f, 0.f, 0.f, 0.f};
#pragma unroll 4
    for (int s = 0; s < 24; ++s) {
        short8 bh = *(const short8*)(bhp + s * 32);
        short8 bl = *(const short8*)(blp + s * 32);
        short8 h0 = *(const short8*)(a0h + s * 32);
        short8 l0 = *(const short8*)(a0l + s * 32);
        short8 h1 = *(const short8*)(a1h + s * 32);
        short8 l1 = *(const short8*)(a1l + s * 32);
        acc0 = __builtin_amdgcn_mfma_f32_16x16x32_bf16(h0, bh, acc0, 0, 0, 0);
        acc0 = __builtin_amdgcn_mfma_f32_16x16x32_bf16(l0, bh, acc0, 0, 0, 0);
        acc0 = __builtin_amdgcn_mfma_f32_16x16x32_bf16(h0, bl, acc0, 0, 0, 0);
        acc1 = __builtin_amdgcn_mfma_f32_16x16x32_bf16(h1, bh, acc1, 0, 0, 0);
        acc1 = __builtin_amdgcn_mfma_f32_16x16x32_bf16(l1, bh, acc1, 0, 0, 0);
        acc1 = __builtin_amdgcn_mfma_f32_16x16x32_bf16(h1, bl, acc1, 0, 0, 0);
    }
    float* cp0 = c1 + (size_t)(m0 + quad * 4) * TD3 + n0 + m;
    float* cp1 = cp0 + (size_t)16 * TD3;
#pragma unroll
    for (int r = 0; r < 4; ++r) {
        cp0[(size_t)r * TD3] = acc0[r];
        cp1[(size_t)r * TD3] = acc1[r];
    }
}

// K3: attn dot (q.k)/8 * sigmoid(filter) -> FHN  (validated, unchanged)
__global__ __launch_bounds__(256) void k3_fhn(const float* __restrict__ c1,
                                              const float* __restrict__ sfilt,
                                              float* __restrict__ fhn) {
    int idx = blockIdx.x * 256 + threadIdx.x;
    if (idx >= Bc * Hc * Kc) return;
    int kk = idx & 31;
    int bh = idx >> 5;
    int h  = bh % Hc;
    int r  = (bh / Hc) * Kc + kk;

    const float* qp = c1 + (size_t)r * TD3 + h * HDc;
    const float* kp = qp + Dc;
    float s = 0.f;
#pragma unroll
    for (int dd = 0; dd < HDc; ++dd) s = fmaf(qp[dd], kp[dd], s);
    s *= 0.125f;

    float filt = 1.f / (1.f + __expf(-sfilt[h * 32 + kk]));
    s *= filt;

    float as    = fabsf(s);
    float scale = fmaxf(as, 1e-6f);
    float sn    = s / scale;
    float gate  = 1.f / (1.f + __expf(-(as - 0.5f) * 10.f));
    float I     = sn * (0.1f + 0.9f * gate);
    const float alpha = 0.08f;
    const float denom = 1.064f;
    float v = 0.f, w = 0.f;
#pragma unroll
    for (int it = 0; it < 2; ++it) {
        float dv = v - (v * v * v) / 3.f - w + I;
        float vn = v + dv;
        float wn = (w + (vn + 0.7f) * alpha) / denom;
        v = fminf(fmaxf(vn, -3.f), 3.f);
        w = fminf(fmaxf(wn, -3.f), 3.f);
    }
    fhn[idx] = v * scale;
}

// K4: proj[r,e] = sum_c (fhn * v_spec[r,c]) * wout[e,c]
// B from bf16 planes; A = fhn-scaled c1_v, inline split (1 split8/step).
// Wave tile 16x16; grid 192 = 768 waves (4x old parallelism).
__global__ __launch_bounds__(256) void k4_proj(const float* __restrict__ c1,
                                               const float* __restrict__ fhn,
                                               const short* __restrict__ wo_hi,
                                               const short* __restrict__ wo_lo,
                                               float* __restrict__ proj) {
    int wave = blockIdx.x * 4 + (threadIdx.x >> 6);   // 192 blocks -> 768 waves
    int lane = threadIdx.x & 63;
    int mb = wave & 15;
    int nt = wave >> 4;                // 48 n-tiles
    int m0 = mb * 16, n0 = nt * 16;
    int m = lane & 15, quad = lane >> 4;

    const short* bhp = wo_hi + (size_t)(n0 + m) * Dc + quad * 8;
    const short* blp = wo_lo + (size_t)(n0 + m) * Dc + quad * 8;

    int r = m0 + m;
    int b = r >> 5, kk = r & 31;
    const float* apx = c1 + (size_t)r * TD3 + 2 * Dc + quad * 8;
    const float* fp  = fhn + (size_t)b * Hc * Kc + kk;

    float4v acc = (float4v){0.f, 0.f, 0.f, 0.f};
#pragma unroll 4
    for (int s = 0; s < 24; ++s) {
        int h = (s * 32 + quad * 8) >> 6;    // whole 8-elem chunk in one head
        float f = fp[h * Kc];
        float av[8];
#pragma unroll
        for (int i = 0; i < 8; ++i) av[i] = apx[s * 32 + i] * f;
        short8 ah, al;
        split8(av, ah, al);
        short8 bh = *(const short8*)(bhp + s * 32);
        short8 bl = *(const short8*)(blp + s * 32);
        acc = __builtin_amdgcn_mfma_f32_16x16x32_bf16(ah, bh, acc, 0, 0, 0);
        acc = __builtin_amdgcn_mfma_f32_16x16x32_bf16(al, bh, acc, 0, 0, 0);
        acc = __builtin_amdgcn_mfma_f32_16x16x32_bf16(ah, bl, acc, 0, 0, 0);
    }
    float* cp = proj + (size_t)(m0 + quad * 4) * Dc + n0 + m;
#pragma unroll
    for (int rr = 0; rr < 4; ++rr) cp[(size_t)rr * Dc] = acc[rr];
}

// ---------------------------------------------------------------------------
// K5: out[b,t,e] = sum_k sb[b,t,k] * proj[b,k,e]  (unchanged, validated)
// ---------------------------------------------------------------------------
__global__ __launch_bounds__(256) void k5_out(const float* __restrict__ proj,
                                              const float* __restrict__ sb,
                                              float* __restrict__ out) {
    __shared__ float pt[32 * 193];

    int tid  = threadIdx.x;
    int w    = tid >> 6;
    int lane = tid & 63;
    int col  = lane & 15;
    int quad = lane >> 4;

    int bid = blockIdx.x;
    int b  = bid >> 8;
    int tt = (bid >> 2) & 63;
    int et = bid & 3;
    int t0 = tt * 64 + w * 16;
    int e0 = et * 192;

    // stage proj[b][0..32)[e0..e0+192): 1536 float4, 6 per thread, coalesced
#pragma unroll
    for (int i = 0; i < 6; ++i) {
        int f4  = tid + i * 256;
        int row = f4 / 48, c4 = f4 % 48;
        float4v v = *(const float4v*)&proj[(size_t)b * Kc * Dc + (size_t)row * Dc + e0 + c4 * 4];
#pragma unroll
        for (int q = 0; q < 4; ++q) pt[row * 193 + c4 * 4 + q] = v[q];
    }

    // A fragment: sb[t0+col][quad*8 .. +8): contiguous per lane
    const float* apx = sb + ((size_t)b * Tc + t0 + col) * Kc + quad * 8;
    short8 ah, al;
    split8(apx, ah, al);

    __syncthreads();

    float4v acc[12];
#pragma unroll
    for (int ni = 0; ni < 12; ++ni) acc[ni] = (float4v){0.f, 0.f, 0.f, 0.f};

#pragma unroll
    for (int ni = 0; ni < 12; ++ni) {
        float bv[8];
#pragma unroll
        for (int j = 0; j < 8; ++j)
            bv[j] = pt[(quad * 8 + j) * 193 + ni * 16 + col];
        short8 bh, bl;
        split8(bv, bh, bl);
        acc[ni] = __builtin_amdgcn_mfma_f32_16x16x32_bf16(ah, bh, acc[ni], 0, 0, 0);
        acc[ni] = __builtin_amdgcn_mfma_f32_16x16x32_bf16(al, bh, acc[ni], 0, 0, 0);
        acc[ni] = __builtin_amdgcn_mfma_f32_16x16x32_bf16(ah, bl, acc[ni], 0, 0, 0);
    }

    float* op = out + ((size_t)b * Tc + t0 + quad * 4) * Dc + e0 + col;
#pragma unroll
    for (int ni = 0; ni < 12; ++ni)
#pragma unroll
        for (int r = 0; r < 4; ++r)
            op[(size_t)r * Dc + ni * 16] = acc[ni][r];
}

extern "C" void kernel_launch(void* const* d_in, const int* in_sizes, int n_in,
                              void* d_out, int out_size, void* d_ws, size_t ws_size,
                              hipStream_t stream) {
    const float* x     = (const float*)d_in[0];
    const float* sb    = (const float*)d_in[1];
    const float* wqkv  = (const float*)d_in[2];
    const float* wout  = (const float*)d_in[3];
    const float* sfilt = (const float*)d_in[4];
    float* out = (float*)d_out;

    // workspace layout (16.53 MB total, same as previous version):
    //   [0, 12.58 MB): pb (k1/k1r)  -- reused after k1r as w_hi/w_lo bf16 planes
    //   then: xs_hi/xs_lo planes (0.75 MB), c1 (2.36 MB), fhn, proj
    float* pb   = (float*)d_ws;                      // [16][B*K*D] 3145728 f
    short* w_hi = (short*)d_ws;                      // [3072][768] shorts (aliases pb)
    short* w_lo = w_hi + (size_t)WALL_F;             // 2,359,296 shorts
    float* base = pb + (size_t)16 * Bc * Kc * Dc;
    short* xs_hi = (short*)base;                     // [256][768] shorts
    short* xs_lo = xs_hi + (size_t)Bc * Kc * Dc;
    float* c1   = base + (size_t)Bc * Kc * Dc;       // [256][2304]  589824 f
    float* fhn  = c1 + (size_t)Bc * Kc * TD3;        // [B][H][K]      3072 f
    float* proj = fhn + (size_t)Bc * Hc * Kc;        // [256][768]   196608 f

    const short* wo_hi = w_hi + (size_t)WQKV_F;      // wout planes start
    const short* wo_lo = w_lo + (size_t)WQKV_F;

    hipLaunchKernelGGL(k1_xspec,   dim3(512),  dim3(256), 0, stream, x, sb, pb);
    hipLaunchKernelGGL(k1r_reduce, dim3(192),  dim3(256), 0, stream, pb, xs_hi, xs_lo);
    hipLaunchKernelGGL(kconv,      dim3(2304), dim3(256), 0, stream, wqkv, wout, w_hi, w_lo);
    hipLaunchKernelGGL(k2_qkv,     dim3(288),  dim3(256), 0, stream, xs_hi, xs_lo, w_hi, w_lo, c1);
    hipLaunchKernelGGL(k3_fhn,     dim3(12),   dim3(256), 0, stream, c1, sfilt, fhn);
    hipLaunchKernelGGL(k4_proj,    dim3(192),  dim3(256), 0, stream, c1, fhn, wo_hi, wo_lo, proj);
    hipLaunchKernelGGL(k5_out,     dim3(2048), dim3(256), 0, stream, proj, sb, out);
}